// Round 7
// baseline (120.745 us; speedup 1.0000x reference)
//
#include <hip/hip_runtime.h>
#include <stdint.h>

#define SEQ   2048
#define DM    512
#define NHEAD 8
#define DKH   64
#define WIN   64
#define NEGV  -1000000000.0f

typedef __attribute__((ext_vector_type(8))) short          short8;
typedef __attribute__((ext_vector_type(4))) float          float4v;
typedef __attribute__((ext_vector_type(8))) unsigned short ushort8v;

__device__ __forceinline__ unsigned short f2bf(float x) {
    uint32_t u = __float_as_uint(x);
    uint32_t r = (u + 0x7FFFu + ((u >> 16) & 1u)) >> 16;
    return (unsigned short)r;
}
__device__ __forceinline__ float bf2f(unsigned short u) {
    return __uint_as_float(((uint32_t)u) << 16);
}

// load 8 f32 and round to 8 bf16
__device__ __forceinline__ ushort8v ldcvt8(const float* __restrict__ p) {
    float4 x0 = *(const float4*)p;
    float4 x1 = *(const float4*)(p + 4);
    ushort8v o;
    o[0] = f2bf(x0.x); o[1] = f2bf(x0.y); o[2] = f2bf(x0.z); o[3] = f2bf(x0.w);
    o[4] = f2bf(x1.x); o[5] = f2bf(x1.y); o[6] = f2bf(x1.z); o[7] = f2bf(x1.w);
    return o;
}

// ---------------------------------------------------------------------------
// bf16 MFMA NT GEMM with on-the-fly f32->bf16 conversion during staging.
// C[m,n] = sum_k A[m,k]*B[n,k] (+bias[n]). K=512, ld=512.
// 128x128 tile, 256 thr = 4 waves (2x2 of 64x64 frag grids).
// Chunk map: c in [0,512): row=c>>2, k8=(c&3)*8; LDS offset 8c — identical
// k-major layout to the r6 (passing) version. Register prefetch overlaps
// next tile's global loads with current tile's MFMA (2 barriers/iter).
// ---------------------------------------------------------------------------
template<bool BIAS, bool OUT_BF16, bool A_F32, bool B_F32>
__device__ __forceinline__ void gemm_body(const void* __restrict__ Ap,
                                          const void* __restrict__ Bp,
                                          const float* __restrict__ bias,
                                          void* __restrict__ Cv)
{
    __shared__ __align__(16) unsigned short As[128 * 32];
    __shared__ __align__(16) unsigned short Bs[128 * 32];

    const int tid  = threadIdx.x;
    const int m0   = blockIdx.x * 128;
    const int n0   = blockIdx.y * 128;
    const int lane = tid & 63;
    const int wave = tid >> 6;
    const int wm   = (wave >> 1) * 64;
    const int wn   = (wave & 1) * 64;
    const int lm   = lane & 15;
    const int lk   = (lane >> 4) * 8;
    const int r    = tid >> 2;            // chunk row (second chunk: r+64)
    const int kc   = (tid & 3) * 8;       // chunk k offset (elements)

    const float* Af = (const float*)Ap;
    const unsigned short* Ab = (const unsigned short*)Ap;
    const float* Bf = (const float*)Bp;
    const unsigned short* Bb = (const unsigned short*)Bp;

    float4v acc[4][4] = {};

    ushort8v a0, a1, b0, b1;
    if (A_F32) { a0 = ldcvt8(Af + (size_t)(m0 + r) * 512 + kc);
                 a1 = ldcvt8(Af + (size_t)(m0 + r + 64) * 512 + kc); }
    else       { a0 = *(const ushort8v*)(Ab + (size_t)(m0 + r) * 512 + kc);
                 a1 = *(const ushort8v*)(Ab + (size_t)(m0 + r + 64) * 512 + kc); }
    if (B_F32) { b0 = ldcvt8(Bf + (size_t)(n0 + r) * 512 + kc);
                 b1 = ldcvt8(Bf + (size_t)(n0 + r + 64) * 512 + kc); }
    else       { b0 = *(const ushort8v*)(Bb + (size_t)(n0 + r) * 512 + kc);
                 b1 = *(const ushort8v*)(Bb + (size_t)(n0 + r + 64) * 512 + kc); }

    for (int k0 = 0; k0 < 512; k0 += 32) {
        // stage current tile (lane-consecutive 16B -> conflict-free)
        *(ushort8v*)(As + (size_t)tid * 8)         = a0;
        *(ushort8v*)(As + (size_t)(tid + 256) * 8) = a1;
        *(ushort8v*)(Bs + (size_t)tid * 8)         = b0;
        *(ushort8v*)(Bs + (size_t)(tid + 256) * 8) = b1;

        // issue next tile's global loads; they complete during the MFMAs
        int kn = k0 + 32;
        if (kn < 512) {
            if (A_F32) { a0 = ldcvt8(Af + (size_t)(m0 + r) * 512 + kn + kc);
                         a1 = ldcvt8(Af + (size_t)(m0 + r + 64) * 512 + kn + kc); }
            else       { a0 = *(const ushort8v*)(Ab + (size_t)(m0 + r) * 512 + kn + kc);
                         a1 = *(const ushort8v*)(Ab + (size_t)(m0 + r + 64) * 512 + kn + kc); }
            if (B_F32) { b0 = ldcvt8(Bf + (size_t)(n0 + r) * 512 + kn + kc);
                         b1 = ldcvt8(Bf + (size_t)(n0 + r + 64) * 512 + kn + kc); }
            else       { b0 = *(const ushort8v*)(Bb + (size_t)(n0 + r) * 512 + kn + kc);
                         b1 = *(const ushort8v*)(Bb + (size_t)(n0 + r + 64) * 512 + kn + kc); }
        }
        __syncthreads();

        short8 av[4], bv[4];
        #pragma unroll
        for (int mt = 0; mt < 4; mt++)
            av[mt] = *(const short8*)(As + (wm + mt * 16 + lm) * 32 + lk);
        #pragma unroll
        for (int nt = 0; nt < 4; nt++)
            bv[nt] = *(const short8*)(Bs + (wn + nt * 16 + lm) * 32 + lk);
        #pragma unroll
        for (int mt = 0; mt < 4; mt++)
            #pragma unroll
            for (int nt = 0; nt < 4; nt++)
                acc[mt][nt] = __builtin_amdgcn_mfma_f32_16x16x32_bf16(
                    av[mt], bv[nt], acc[mt][nt], 0, 0, 0);
        __syncthreads();
    }

    const int r0 = (lane >> 4) * 4;
    const int cn = lane & 15;
    #pragma unroll
    for (int nt = 0; nt < 4; nt++) {
        int gcol = n0 + wn + nt * 16 + cn;
        float b = BIAS ? bias[gcol] : 0.f;
        #pragma unroll
        for (int mt = 0; mt < 4; mt++) {
            int grow = m0 + wm + mt * 16 + r0;
            #pragma unroll
            for (int reg = 0; reg < 4; reg++) {
                float val = acc[mt][nt][reg] + b;
                if (OUT_BF16)
                    ((unsigned short*)Cv)[(size_t)(grow + reg) * 512 + gcol] = f2bf(val);
                else
                    ((float*)Cv)[(size_t)(grow + reg) * 512 + gcol] = val;
            }
        }
    }
}

__global__ __launch_bounds__(256)
void qkv_gemm_kernel(const float* __restrict__ q, const float* __restrict__ k,
                     const float* __restrict__ v,
                     const float* __restrict__ Wq, const float* __restrict__ Wk,
                     const float* __restrict__ Wv,
                     unsigned short* __restrict__ Qp, unsigned short* __restrict__ Kp,
                     unsigned short* __restrict__ Vp)
{
    const float *A, *B; unsigned short* C;
    if (blockIdx.z == 0)      { A = q; B = Wq; C = Qp; }
    else if (blockIdx.z == 1) { A = k; B = Wk; C = Kp; }
    else                      { A = v; B = Wv; C = Vp; }
    gemm_body<false, true, true, true>(A, B, nullptr, C);
}

__global__ __launch_bounds__(256)
void out_gemm_kernel(const unsigned short* __restrict__ ctxb,
                     const float* __restrict__ Wo,
                     const float* __restrict__ bo, float* __restrict__ out)
{
    gemm_body<true, false, false, true>(ctxb, Wo, bo, out);
}

// ---------------------------------------------------------------------------
// MFMA windowed attention (UNCHANGED from r6 — passing). Block = 64 q x 1 head.
// Vt stride 152 ushorts, keys 128..151 zeroed (r4/r5 NaN fix).
// ---------------------------------------------------------------------------
#define VTS 152

__global__ __launch_bounds__(256)
void attn_kernel(const unsigned short* __restrict__ Qp,
                 const unsigned short* __restrict__ Kp,
                 const unsigned short* __restrict__ Vp,
                 unsigned short* __restrict__ ctxb,
                 float* __restrict__ attnw)
{
    __shared__ __align__(16) unsigned short Qs[64 * 72];    // [q_local][64 k]
    __shared__ __align__(16) unsigned short Ks[128 * 72];   // [key_local][64 k]
    __shared__ __align__(16) unsigned short Vt[64 * VTS];   // [d][key_local 0..151]
    __shared__ __align__(16) unsigned short Ps[4][16][96];  // [wave][q][kk]

    const int h   = blockIdx.y;
    const int q0  = blockIdx.x * 64;
    const int tid = threadIdx.x;

    for (int c = tid; c < 512; c += 256) {
        int row = c >> 3, ch = c & 7;
        *(ushort8v*)&Qs[row * 72 + ch * 8] =
            *(const ushort8v*)&Qp[(size_t)(q0 + row) * 512 + h * 64 + ch * 8];
    }
    for (int c = tid; c < 1024; c += 256) {
        int row = c >> 3, ch = c & 7;
        int g = q0 - 64 + row;
        ushort8v val = {0, 0, 0, 0, 0, 0, 0, 0};
        if (g >= 0)
            val = *(const ushort8v*)&Kp[(size_t)g * 512 + h * 64 + ch * 8];
        *(ushort8v*)&Ks[row * 72 + ch * 8] = val;
    }
    {
        int key = tid >> 1, dh = tid & 1;
        int g = q0 - 64 + key;
        ushort8v vv[4];
        #pragma unroll
        for (int j = 0; j < 4; j++) {
            ushort8v z = {0, 0, 0, 0, 0, 0, 0, 0};
            vv[j] = (g >= 0)
                ? *(const ushort8v*)&Vp[(size_t)g * 512 + h * 64 + dh * 32 + j * 8]
                : z;
        }
        #pragma unroll
        for (int j = 0; j < 4; j++)
            #pragma unroll
            for (int e = 0; e < 8; e++)
                Vt[(dh * 32 + j * 8 + e) * VTS + key] = vv[j][e];
    }
    // zero pad keys 128..151 for all 64 d-rows (deterministic 0*0 tail)
    for (int t = tid; t < 64 * 24; t += 256) {
        int d = t / 24, c = 128 + (t % 24);
        Vt[d * VTS + c] = 0;
    }
    __syncthreads();

    const int lane = tid & 63;
    const int w    = tid >> 6;
    const int lm   = lane & 15;
    const int g16  = lane >> 4;
    const int lk8  = g16 * 8;

    short8 av0 = *(const short8*)&Qs[(w * 16 + lm) * 72 + lk8];
    short8 av1 = *(const short8*)&Qs[(w * 16 + lm) * 72 + 32 + lk8];
    float4v sc[5];
    #pragma unroll
    for (int kt = 0; kt < 5; kt++) {
        const unsigned short* kr = &Ks[(w * 16 + kt * 16 + lm) * 72];
        short8 b0 = *(const short8*)(kr + lk8);
        short8 b1 = *(const short8*)(kr + 32 + lk8);
        float4v a = {0.f, 0.f, 0.f, 0.f};
        a = __builtin_amdgcn_mfma_f32_16x16x32_bf16(av0, b0, a, 0, 0, 0);
        a = __builtin_amdgcn_mfma_f32_16x16x32_bf16(av1, b1, a, 0, 0, 0);
        sc[kt] = a;
    }

    float v[5][4];
    #pragma unroll
    for (int kt = 0; kt < 5; kt++) {
        int kk = kt * 16 + lm;
        int g  = q0 - 64 + w * 16 + kk;
        #pragma unroll
        for (int reg = 0; reg < 4; reg++) {
            int rr = g16 * 4 + reg;
            bool valid = (kk >= rr) && (kk <= rr + 64) && (g >= 0);
            v[kt][reg] = valid
                ? sc[kt][reg] * 0.125f + 0.1f * __expf(-0.1f * (float)(64 + rr - kk))
                : NEGV;
        }
    }

    float mx[4], sm[4];
    #pragma unroll
    for (int reg = 0; reg < 4; reg++) {
        float m = v[0][reg];
        #pragma unroll
        for (int kt = 1; kt < 5; kt++) m = fmaxf(m, v[kt][reg]);
        mx[reg] = m;
    }
    #pragma unroll
    for (int off = 1; off < 16; off <<= 1)
        #pragma unroll
        for (int reg = 0; reg < 4; reg++)
            mx[reg] = fmaxf(mx[reg], __shfl_xor(mx[reg], off));
    float p[5][4];
    #pragma unroll
    for (int reg = 0; reg < 4; reg++) {
        float s = 0.f;
        #pragma unroll
        for (int kt = 0; kt < 5; kt++) {
            float e = __expf(v[kt][reg] - mx[reg]);
            p[kt][reg] = e;
            s += e;
        }
        sm[reg] = s;
    }
    #pragma unroll
    for (int off = 1; off < 16; off <<= 1)
        #pragma unroll
        for (int reg = 0; reg < 4; reg++)
            sm[reg] += __shfl_xor(sm[reg], off);
    #pragma unroll
    for (int reg = 0; reg < 4; reg++) {
        float inv = 1.f / sm[reg];
        #pragma unroll
        for (int kt = 0; kt < 5; kt++) p[kt][reg] *= inv;
    }

    #pragma unroll
    for (int kt = 0; kt < 5; kt++)
        #pragma unroll
        for (int reg = 0; reg < 4; reg++)
            Ps[w][g16 * 4 + reg][kt * 16 + lm] = f2bf(p[kt][reg]);
    #pragma unroll
    for (int reg = 0; reg < 4; reg++)
        Ps[w][g16 * 4 + reg][80 + lm] = 0;

    // Cross-lane LDS RAW: Ps written by rows g16*4+reg, read below by rows lm.
    __syncthreads();

    float4v oacc[4] = {};
    #pragma unroll
    for (int ks = 0; ks < 3; ks++) {
        short8 pa = *(const short8*)&Ps[w][lm][ks * 32 + lk8];
        #pragma unroll
        for (int nt = 0; nt < 4; nt++) {
            short8 vb = *(const short8*)&Vt[(nt * 16 + lm) * VTS + w * 16 + ks * 32 + lk8];
            oacc[nt] = __builtin_amdgcn_mfma_f32_16x16x32_bf16(pa, vb, oacc[nt], 0, 0, 0);
        }
    }

    #pragma unroll
    for (int nt = 0; nt < 4; nt++)
        #pragma unroll
        for (int reg = 0; reg < 4; reg++) {
            int i = q0 + w * 16 + g16 * 4 + reg;
            ctxb[(size_t)i * 512 + h * 64 + nt * 16 + lm] = f2bf(oacc[nt][reg]);
        }

    __syncthreads();

    for (int t = tid; t < 64 * 128; t += 256) {
        int ql = t >> 7, slot = t & 127;
        int i  = q0 + ql;
        float val = 0.f;
        if (q0 == 0) {
            if (slot <= ql) {
                int kk = (ql & 15) + slot + 64 - ql;
                val = bf2f(Ps[ql >> 4][ql & 15][kk]);
            }
        } else if (q0 == SEQ - 64) {
            if (slot <= 64) {
                int kk = (ql & 15) + slot;
                val = bf2f(Ps[ql >> 4][ql & 15][kk]);
            }
        }
        attnw[((size_t)h * SEQ + i) * 2 * WIN + slot] = val;
    }
}

// ---------------------------------------------------------------------------
extern "C" void kernel_launch(void* const* d_in, const int* in_sizes, int n_in,
                              void* d_out, int out_size, void* d_ws, size_t ws_size,
                              hipStream_t stream)
{
    const float* query = (const float*)d_in[0];
    const float* key   = (const float*)d_in[1];
    const float* value = (const float*)d_in[2];
    const float* Wq    = (const float*)d_in[3];
    const float* Wk    = (const float*)d_in[4];
    const float* Wv    = (const float*)d_in[5];
    const float* Wo    = (const float*)d_in[6];
    const float* bo    = (const float*)d_in[7];

    float* out   = (float*)d_out;                 // 2048*512 f32
    float* attnw = out + SEQ * DM;                // 8*2048*128 f32

    unsigned short* Qp   = (unsigned short*)d_ws;       // bf16 projections
    unsigned short* Kp   = Qp + 1048576;
    unsigned short* Vp   = Kp + 1048576;
    unsigned short* ctxb = Vp + 1048576;

    dim3 g1(SEQ / 128, DM / 128, 3);
    qkv_gemm_kernel<<<g1, 256, 0, stream>>>(query, key, value, Wq, Wk, Wv,
                                            Qp, Kp, Vp);

    dim3 g2(SEQ / 64, NHEAD);
    attn_kernel<<<g2, 256, 0, stream>>>(Qp, Kp, Vp, ctxb, attnw);

    dim3 g3(SEQ / 128, DM / 128);
    out_gemm_kernel<<<g3, 256, 0, stream>>>(ctxb, Wo, bo, out);
}

// Round 8
// 113.782 us; speedup vs baseline: 1.0612x; 1.0612x over previous
//
#include <hip/hip_runtime.h>
#include <stdint.h>

#define SEQ   2048
#define DM    512
#define NHEAD 8
#define DKH   64
#define WIN   64
#define NEGV  -1000000000.0f

typedef __attribute__((ext_vector_type(8))) short          short8;
typedef __attribute__((ext_vector_type(4))) float          float4v;
typedef __attribute__((ext_vector_type(8))) unsigned short ushort8v;

__device__ __forceinline__ unsigned short f2bf(float x) {
    uint32_t u = __float_as_uint(x);
    uint32_t r = (u + 0x7FFFu + ((u >> 16) & 1u)) >> 16;
    return (unsigned short)r;
}
__device__ __forceinline__ float bf2f(unsigned short u) {
    return __uint_as_float(((uint32_t)u) << 16);
}

// async 16B global -> LDS (wave-uniform base + lane*16 pattern)
__device__ __forceinline__ void async_cp16(const void* g, void* lds) {
    __builtin_amdgcn_global_load_lds(
        (const __attribute__((address_space(1))) unsigned int*)(uintptr_t)g,
        (__attribute__((address_space(3))) unsigned int*)(uint32_t)(uintptr_t)lds,
        16, 0, 0);
}

// ---------------------------------------------------------------------------
// Fused f32 -> bf16 cast of q,k,v (1M each) + Wq,Wk,Wv,Wo (256K each).
// NOTE (r7 lesson): keeping this as a separate HBM-bound pass is FASTER than
// folding the cast into GEMM staging — inline f2bf repack VALU-dominates the
// GEMM inner loop (m80-class failure) and loses the async global_load_lds path.
// ---------------------------------------------------------------------------
__global__ __launch_bounds__(256)
void cast7_kernel(const float* __restrict__ q, const float* __restrict__ k,
                  const float* __restrict__ v, const float* __restrict__ wq,
                  const float* __restrict__ wk, const float* __restrict__ wv,
                  const float* __restrict__ wo, unsigned short* __restrict__ dst)
{
    int g = (blockIdx.x * 256 + threadIdx.x) * 8;   // < 4194304
    const float* src; int off;
    if      (g < 1048576) { src = q;  off = g; }
    else if (g < 2097152) { src = k;  off = g - 1048576; }
    else if (g < 3145728) { src = v;  off = g - 2097152; }
    else if (g < 3407872) { src = wq; off = g - 3145728; }
    else if (g < 3670016) { src = wk; off = g - 3407872; }
    else if (g < 3932160) { src = wv; off = g - 3670016; }
    else                  { src = wo; off = g - 3932160; }
    float4 x0 = *(const float4*)(src + off);
    float4 x1 = *(const float4*)(src + off + 4);
    ushort8v o;
    o[0] = f2bf(x0.x); o[1] = f2bf(x0.y); o[2] = f2bf(x0.z); o[3] = f2bf(x0.w);
    o[4] = f2bf(x1.x); o[5] = f2bf(x1.y); o[6] = f2bf(x1.z); o[7] = f2bf(x1.w);
    *(ushort8v*)(dst + g) = o;
}

// ---------------------------------------------------------------------------
// bf16 MFMA NT GEMM: C[m,n] = sum_k A[m,k]*B[n,k] (+bias[n]).
// OUT_BF16 selects bf16 or f32 output. 128x128 tile, 256 thr = 4 waves.
// Staging via async global_load_lds width=16 (r7 showed register-pipelined
// staging with inline cast regresses ~14 us on the qkv GEMM).
// ---------------------------------------------------------------------------
template<bool BIAS, bool OUT_BF16>
__device__ __forceinline__ void gemm_mfma_body(const unsigned short* __restrict__ A,
                                               const unsigned short* __restrict__ B,
                                               const float* __restrict__ bias,
                                               void* __restrict__ Cv)
{
    __shared__ __align__(16) unsigned short As[128 * 32];
    __shared__ __align__(16) unsigned short Bs[128 * 32];

    const int tid  = threadIdx.x;
    const int m0   = blockIdx.x * 128;
    const int n0   = blockIdx.y * 128;
    const int lane = tid & 63;
    const int wave = tid >> 6;
    const int wm   = (wave >> 1) * 64;
    const int wn   = (wave & 1) * 64;
    const int lm   = lane & 15;
    const int lk   = (lane >> 4) * 8;

    float4v acc[4][4] = {};

    for (int k0 = 0; k0 < 512; k0 += 32) {
        #pragma unroll
        for (int h = 0; h < 2; h++) {
            int c  = tid + h * 256;
            int r  = c >> 2;
            int kc = (c & 3) * 8;
            async_cp16(A + (size_t)(m0 + r) * 512 + k0 + kc, As + c * 8);
            async_cp16(B + (size_t)(n0 + r) * 512 + k0 + kc, Bs + c * 8);
        }
        __syncthreads();

        short8 av[4], bv[4];
        #pragma unroll
        for (int mt = 0; mt < 4; mt++)
            av[mt] = *(const short8*)(As + (wm + mt * 16 + lm) * 32 + lk);
        #pragma unroll
        for (int nt = 0; nt < 4; nt++)
            bv[nt] = *(const short8*)(Bs + (wn + nt * 16 + lm) * 32 + lk);
        #pragma unroll
        for (int mt = 0; mt < 4; mt++)
            #pragma unroll
            for (int nt = 0; nt < 4; nt++)
                acc[mt][nt] = __builtin_amdgcn_mfma_f32_16x16x32_bf16(
                    av[mt], bv[nt], acc[mt][nt], 0, 0, 0);
        __syncthreads();
    }

    const int r0 = (lane >> 4) * 4;
    const int cn = lane & 15;
    #pragma unroll
    for (int nt = 0; nt < 4; nt++) {
        int gcol = n0 + wn + nt * 16 + cn;
        float b = BIAS ? bias[gcol] : 0.f;
        #pragma unroll
        for (int mt = 0; mt < 4; mt++) {
            int grow = m0 + wm + mt * 16 + r0;
            #pragma unroll
            for (int reg = 0; reg < 4; reg++) {
                float val = acc[mt][nt][reg] + b;
                if (OUT_BF16)
                    ((unsigned short*)Cv)[(size_t)(grow + reg) * 512 + gcol] = f2bf(val);
                else
                    ((float*)Cv)[(size_t)(grow + reg) * 512 + gcol] = val;
            }
        }
    }
}

__global__ __launch_bounds__(256)
void qkv_gemm_kernel(const unsigned short* __restrict__ qb,
                     const unsigned short* __restrict__ kb,
                     const unsigned short* __restrict__ vb,
                     const unsigned short* __restrict__ wqb,
                     const unsigned short* __restrict__ wkb,
                     const unsigned short* __restrict__ wvb,
                     unsigned short* __restrict__ Qp, unsigned short* __restrict__ Kp,
                     unsigned short* __restrict__ Vp)
{
    const unsigned short *A, *B; unsigned short* C;
    if (blockIdx.z == 0)      { A = qb; B = wqb; C = Qp; }
    else if (blockIdx.z == 1) { A = kb; B = wkb; C = Kp; }
    else                      { A = vb; B = wvb; C = Vp; }
    gemm_mfma_body<false, true>(A, B, nullptr, C);
}

__global__ __launch_bounds__(256)
void out_gemm_kernel(const unsigned short* __restrict__ ctxb,
                     const unsigned short* __restrict__ wob,
                     const float* __restrict__ bo, float* __restrict__ out)
{
    gemm_mfma_body<true, false>(ctxb, wob, bo, out);
}

// ---------------------------------------------------------------------------
// MFMA windowed attention. Block = 64 queries x 1 head, 256 thr = 4 waves.
// Wave w owns queries q0+w*16..+15 and local key rows w*16..w*16+79.
// Vt stride = 152 ushorts (304B = 19x16B aligned; 2-way bank alias = free).
// Keys 128..151 explicitly zeroed: wave 3's PV reads reach key 143 with
// zero P operands — uninit LDS there was the r4/r5 NaN source (0*NaN=NaN).
// ---------------------------------------------------------------------------
#define VTS 152

__global__ __launch_bounds__(256)
void attn_kernel(const unsigned short* __restrict__ Qp,
                 const unsigned short* __restrict__ Kp,
                 const unsigned short* __restrict__ Vp,
                 unsigned short* __restrict__ ctxb,
                 float* __restrict__ attnw)
{
    __shared__ __align__(16) unsigned short Qs[64 * 72];    // [q_local][64 k]
    __shared__ __align__(16) unsigned short Ks[128 * 72];   // [key_local][64 k]
    __shared__ __align__(16) unsigned short Vt[64 * VTS];   // [d][key_local 0..151]
    __shared__ __align__(16) unsigned short Ps[4][16][96];  // [wave][q][kk]

    const int h   = blockIdx.y;
    const int q0  = blockIdx.x * 64;
    const int tid = threadIdx.x;

    for (int c = tid; c < 512; c += 256) {
        int row = c >> 3, ch = c & 7;
        *(ushort8v*)&Qs[row * 72 + ch * 8] =
            *(const ushort8v*)&Qp[(size_t)(q0 + row) * 512 + h * 64 + ch * 8];
    }
    for (int c = tid; c < 1024; c += 256) {
        int row = c >> 3, ch = c & 7;
        int g = q0 - 64 + row;
        ushort8v val = {0, 0, 0, 0, 0, 0, 0, 0};
        if (g >= 0)
            val = *(const ushort8v*)&Kp[(size_t)g * 512 + h * 64 + ch * 8];
        *(ushort8v*)&Ks[row * 72 + ch * 8] = val;
    }
    {
        int key = tid >> 1, dh = tid & 1;
        int g = q0 - 64 + key;
        ushort8v vv[4];
        #pragma unroll
        for (int j = 0; j < 4; j++) {
            ushort8v z = {0, 0, 0, 0, 0, 0, 0, 0};
            vv[j] = (g >= 0)
                ? *(const ushort8v*)&Vp[(size_t)g * 512 + h * 64 + dh * 32 + j * 8]
                : z;
        }
        #pragma unroll
        for (int j = 0; j < 4; j++)
            #pragma unroll
            for (int e = 0; e < 8; e++)
                Vt[(dh * 32 + j * 8 + e) * VTS + key] = vv[j][e];
    }
    // zero pad keys 128..151 for all 64 d-rows (deterministic 0*0 tail)
    for (int t = tid; t < 64 * 24; t += 256) {
        int d = t / 24, c = 128 + (t % 24);
        Vt[d * VTS + c] = 0;
    }
    __syncthreads();

    const int lane = tid & 63;
    const int w    = tid >> 6;
    const int lm   = lane & 15;
    const int g16  = lane >> 4;
    const int lk8  = g16 * 8;

    short8 av0 = *(const short8*)&Qs[(w * 16 + lm) * 72 + lk8];
    short8 av1 = *(const short8*)&Qs[(w * 16 + lm) * 72 + 32 + lk8];
    float4v sc[5];
    #pragma unroll
    for (int kt = 0; kt < 5; kt++) {
        const unsigned short* kr = &Ks[(w * 16 + kt * 16 + lm) * 72];
        short8 b0 = *(const short8*)(kr + lk8);
        short8 b1 = *(const short8*)(kr + 32 + lk8);
        float4v a = {0.f, 0.f, 0.f, 0.f};
        a = __builtin_amdgcn_mfma_f32_16x16x32_bf16(av0, b0, a, 0, 0, 0);
        a = __builtin_amdgcn_mfma_f32_16x16x32_bf16(av1, b1, a, 0, 0, 0);
        sc[kt] = a;
    }

    float v[5][4];
    #pragma unroll
    for (int kt = 0; kt < 5; kt++) {
        int kk = kt * 16 + lm;
        int g  = q0 - 64 + w * 16 + kk;
        #pragma unroll
        for (int reg = 0; reg < 4; reg++) {
            int rr = g16 * 4 + reg;
            bool valid = (kk >= rr) && (kk <= rr + 64) && (g >= 0);
            v[kt][reg] = valid
                ? sc[kt][reg] * 0.125f + 0.1f * __expf(-0.1f * (float)(64 + rr - kk))
                : NEGV;
        }
    }

    float mx[4], sm[4];
    #pragma unroll
    for (int reg = 0; reg < 4; reg++) {
        float m = v[0][reg];
        #pragma unroll
        for (int kt = 1; kt < 5; kt++) m = fmaxf(m, v[kt][reg]);
        mx[reg] = m;
    }
    #pragma unroll
    for (int off = 1; off < 16; off <<= 1)
        #pragma unroll
        for (int reg = 0; reg < 4; reg++)
            mx[reg] = fmaxf(mx[reg], __shfl_xor(mx[reg], off));
    float p[5][4];
    #pragma unroll
    for (int reg = 0; reg < 4; reg++) {
        float s = 0.f;
        #pragma unroll
        for (int kt = 0; kt < 5; kt++) {
            float e = __expf(v[kt][reg] - mx[reg]);
            p[kt][reg] = e;
            s += e;
        }
        sm[reg] = s;
    }
    #pragma unroll
    for (int off = 1; off < 16; off <<= 1)
        #pragma unroll
        for (int reg = 0; reg < 4; reg++)
            sm[reg] += __shfl_xor(sm[reg], off);
    #pragma unroll
    for (int reg = 0; reg < 4; reg++) {
        float inv = 1.f / sm[reg];
        #pragma unroll
        for (int kt = 0; kt < 5; kt++) p[kt][reg] *= inv;
    }

    #pragma unroll
    for (int kt = 0; kt < 5; kt++)
        #pragma unroll
        for (int reg = 0; reg < 4; reg++)
            Ps[w][g16 * 4 + reg][kt * 16 + lm] = f2bf(p[kt][reg]);
    #pragma unroll
    for (int reg = 0; reg < 4; reg++)
        Ps[w][g16 * 4 + reg][80 + lm] = 0;

    // Cross-lane LDS RAW: Ps written by rows g16*4+reg, read below by rows lm.
    __syncthreads();

    float4v oacc[4] = {};
    #pragma unroll
    for (int ks = 0; ks < 3; ks++) {
        short8 pa = *(const short8*)&Ps[w][lm][ks * 32 + lk8];
        #pragma unroll
        for (int nt = 0; nt < 4; nt++) {
            short8 vb = *(const short8*)&Vt[(nt * 16 + lm) * VTS + w * 16 + ks * 32 + lk8];
            oacc[nt] = __builtin_amdgcn_mfma_f32_16x16x32_bf16(pa, vb, oacc[nt], 0, 0, 0);
        }
    }

    #pragma unroll
    for (int nt = 0; nt < 4; nt++)
        #pragma unroll
        for (int reg = 0; reg < 4; reg++) {
            int i = q0 + w * 16 + g16 * 4 + reg;
            ctxb[(size_t)i * 512 + h * 64 + nt * 16 + lm] = f2bf(oacc[nt][reg]);
        }

    __syncthreads();

    for (int t = tid; t < 64 * 128; t += 256) {
        int ql = t >> 7, slot = t & 127;
        int i  = q0 + ql;
        float val = 0.f;
        if (q0 == 0) {
            if (slot <= ql) {
                int kk = (ql & 15) + slot + 64 - ql;
                val = bf2f(Ps[ql >> 4][ql & 15][kk]);
            }
        } else if (q0 == SEQ - 64) {
            if (slot <= 64) {
                int kk = (ql & 15) + slot;
                val = bf2f(Ps[ql >> 4][ql & 15][kk]);
            }
        }
        attnw[((size_t)h * SEQ + i) * 2 * WIN + slot] = val;
    }
}

// ---------------------------------------------------------------------------
extern "C" void kernel_launch(void* const* d_in, const int* in_sizes, int n_in,
                              void* d_out, int out_size, void* d_ws, size_t ws_size,
                              hipStream_t stream)
{
    const float* query = (const float*)d_in[0];
    const float* key   = (const float*)d_in[1];
    const float* value = (const float*)d_in[2];
    const float* Wq    = (const float*)d_in[3];
    const float* Wk    = (const float*)d_in[4];
    const float* Wv    = (const float*)d_in[5];
    const float* Wo    = (const float*)d_in[6];
    const float* bo    = (const float*)d_in[7];

    float* out   = (float*)d_out;                 // 2048*512 f32
    float* attnw = out + SEQ * DM;                // 8*2048*128 f32

    unsigned short* qb   = (unsigned short*)d_ws;       // casts of inputs
    unsigned short* kb   = qb  + 1048576;
    unsigned short* vb   = kb  + 1048576;
    unsigned short* wqb  = vb  + 1048576;
    unsigned short* wkb  = wqb + 262144;
    unsigned short* wvb  = wkb + 262144;
    unsigned short* wob  = wvb + 262144;
    unsigned short* Qp   = wob + 262144;                // projected, bf16
    unsigned short* Kp   = Qp  + 1048576;
    unsigned short* Vp   = Kp  + 1048576;
    unsigned short* ctxb = Vp  + 1048576;

    cast7_kernel<<<2048, 256, 0, stream>>>(query, key, value, Wq, Wk, Wv, Wo, qb);

    dim3 g1(SEQ / 128, DM / 128, 3);
    qkv_gemm_kernel<<<g1, 256, 0, stream>>>(qb, kb, vb, wqb, wkb, wvb, Qp, Kp, Vp);

    dim3 g2(SEQ / 64, NHEAD);
    attn_kernel<<<g2, 256, 0, stream>>>(Qp, Kp, Vp, ctxb, attnw);

    dim3 g3(SEQ / 128, DM / 128);
    out_gemm_kernel<<<g3, 256, 0, stream>>>(ctxb, wob, bo, out);
}